// Round 2
// baseline (504.885 us; speedup 1.0000x reference)
//
#include <hip/hip_runtime.h>
#include <hip/hip_bf16.h>

// KMeans predict: ids = argmin_k ||c_k||^2 - 2 x.c_k    (N=500000, D=64, K=1024)
// Pass 1: fp16 MFMA scores with C-init = -0.5*||c||^2 (fp32-exact), track
//         best + runner-up per point; uncertain (gap < MARGIN) -> list.
// Pass 2: fp64-exact recompute for uncertain points (authoritative).

#define N_PTS 500000
#define DIM   64
#define K_CENT 1024
#define MARGIN 0.0625f   // in s~ = -0.5*m2 + dot units (score gap = 2x this)

typedef _Float16 half8 __attribute__((ext_vector_type(8)));
typedef float    floatx4 __attribute__((ext_vector_type(4)));

__device__ __forceinline__ float sel4f(int r, float a, float b, float c, float d) {
    return r == 0 ? a : (r == 1 ? b : (r == 2 ? c : d));
}
__device__ __forceinline__ int sel4i(int r, int a, int b, int c, int d) {
    return r == 0 ? a : (r == 1 ? b : (r == 2 ? c : d));
}

// ---------------------------------------------------------------- pass 1 ----
// 512 threads = 8 waves; wave handles 64 points (4 M-tiles of 16).
// Centers staged to LDS fp16 in 4 stages of 256; padded stride 72 halves
// (144 B) so 16 B B-frag reads spread across banks (2-way max = free).
__launch_bounds__(512, 4)
__global__ void kmeans_pass1(const float* __restrict__ x,
                             const float* __restrict__ centers,
                             int* __restrict__ out,
                             int* __restrict__ counter,
                             int* __restrict__ ulist,
                             int capacity)
{
    __shared__ __align__(16) _Float16 ldsC[256 * 72];
    __shared__ float negm2[256];

    const int tid  = threadIdx.x;
    const int lane = tid & 63;
    const int wave = tid >> 6;
    const int l15  = lane & 15;
    const int quad = lane >> 4;

    const int baseP = blockIdx.x * 512 + wave * 64;

    // ---- A fragments: 4 M-tiles, 2 K-halves each. A[m=l15][k=quad*8+j] ----
    half8 afrag[4][2];
    #pragma unroll
    for (int mt = 0; mt < 4; ++mt) {
        int p = baseP + mt * 16 + l15;
        if (p > N_PTS - 1) p = N_PTS - 1;           // tail clamp (dup row, unused)
        const float* xr = x + (size_t)p * DIM + quad * 8;
        #pragma unroll
        for (int h = 0; h < 2; ++h) {
            float4 f0 = *(const float4*)(xr + h * 32);
            float4 f1 = *(const float4*)(xr + h * 32 + 4);
            half8 a;
            a[0] = (_Float16)f0.x; a[1] = (_Float16)f0.y;
            a[2] = (_Float16)f0.z; a[3] = (_Float16)f0.w;
            a[4] = (_Float16)f1.x; a[5] = (_Float16)f1.y;
            a[6] = (_Float16)f1.z; a[7] = (_Float16)f1.w;
            afrag[mt][h] = a;
        }
    }

    float m1[4][4], m2v[4][4];
    int   ctb[4][4];
    #pragma unroll
    for (int mt = 0; mt < 4; ++mt)
        #pragma unroll
        for (int r = 0; r < 4; ++r) { m1[mt][r] = -1e30f; m2v[mt][r] = -1e30f; ctb[mt][r] = 0; }

    for (int s = 0; s < 4; ++s) {
        __syncthreads();                             // prev-stage readers done
        // ---- stage 256 centers: thread t -> center t>>1, half t&1 ----
        {
            const int c = tid >> 1, h = tid & 1;
            const float* src = centers + (size_t)(s * 256 + c) * DIM + h * 32;
            float ss = 0.f;
            #pragma unroll 2
            for (int j = 0; j < 8; ++j) {
                float4 v = *(const float4*)(src + j * 4);
                ss = fmaf(v.x, v.x, fmaf(v.y, v.y, fmaf(v.z, v.z, fmaf(v.w, v.w, ss))));
                union { _Float16 hh[4]; uint2 u; } pk;
                pk.hh[0] = (_Float16)v.x; pk.hh[1] = (_Float16)v.y;
                pk.hh[2] = (_Float16)v.z; pk.hh[3] = (_Float16)v.w;
                *(uint2*)&ldsC[c * 72 + h * 32 + j * 4] = pk.u;
            }
            float oss = __shfl_xor(ss, 1);
            if (h == 0) negm2[c] = -0.5f * (ss + oss);
        }
        __syncthreads();

        // ---- 16 center-tiles of 16 in this stage ----
        #pragma unroll 2
        for (int ctl = 0; ctl < 16; ++ctl) {
            const float ic = negm2[ctl * 16 + l15];
            const _Float16* bp = &ldsC[(ctl * 16 + l15) * 72 + quad * 8];
            half8 b0 = *(const half8*)bp;            // k = 0..31
            half8 b1 = *(const half8*)(bp + 32);     // k = 32..63
            const int ct = s * 16 + ctl;
            #pragma unroll
            for (int mt = 0; mt < 4; ++mt) {
                floatx4 acc = {ic, ic, ic, ic};      // -0.5*||c||^2 (exact fp32)
                acc = __builtin_amdgcn_mfma_f32_16x16x32_f16(afrag[mt][0], b0, acc, 0, 0, 0);
                acc = __builtin_amdgcn_mfma_f32_16x16x32_f16(afrag[mt][1], b1, acc, 0, 0, 0);
                #pragma unroll
                for (int r = 0; r < 4; ++r) {
                    float sc = acc[r];               // s~; argmax == argmin score
                    m2v[mt][r] = fmaxf(m2v[mt][r], fminf(sc, m1[mt][r]));
                    bool gt = sc > m1[mt][r];        // strict: first-index ties
                    m1[mt][r] = gt ? sc : m1[mt][r];
                    ctb[mt][r] = gt ? ct : ctb[mt][r];
                }
            }
        }
    }

    // ---- per-point reduce across the 16-lane column group, then write ----
    #pragma unroll
    for (int mt = 0; mt < 4; ++mt) {
        #pragma unroll
        for (int r = 0; r < 4; ++r) {
            float a1 = m1[mt][r], a2 = m2v[mt][r];
            int   id = ctb[mt][r] * 16 + l15;        // full center index
            #pragma unroll
            for (int m = 1; m <= 8; m <<= 1) {
                float o1 = __shfl_xor(a1, m);
                float o2 = __shfl_xor(a2, m);
                int  oid = __shfl_xor(id, m);
                a2 = fmaxf(fmaxf(a2, o2), fminf(a1, o1));
                bool take = (o1 > a1) || (o1 == a1 && oid < id);
                a1 = take ? o1 : a1;
                id = take ? oid : id;
            }
            m1[mt][r] = a1; m2v[mt][r] = a2; ctb[mt][r] = id;
        }
        if (l15 < 4) {                                // writer lanes: reg = l15
            const int r = l15;
            const int p = baseP + mt * 16 + quad * 4 + r;
            if (p < N_PTS) {
                float a1 = sel4f(r, m1[mt][0], m1[mt][1], m1[mt][2], m1[mt][3]);
                float a2 = sel4f(r, m2v[mt][0], m2v[mt][1], m2v[mt][2], m2v[mt][3]);
                int   id = sel4i(r, ctb[mt][0], ctb[mt][1], ctb[mt][2], ctb[mt][3]);
                out[p] = id;
                if (a1 - a2 < MARGIN) {               // too close for fp16 -> recheck
                    int slot = atomicAdd(counter, 1);
                    if (slot < capacity) ulist[slot] = p;
                }
            }
        }
    }
}

// ---------------------------------------------------------------- pass 2 ----
// fp64-exact recompute for uncertain points (fp32 inputs widen exactly).
// 16 points per block-iteration; centers stream from L2 (256 KB resident).
#define P2_PTS 16
__launch_bounds__(256, 4)
__global__ void kmeans_pass2(const float* __restrict__ x,
                             const float* __restrict__ centers,
                             int* __restrict__ out,
                             const int* __restrict__ counter,
                             const int* __restrict__ ulist,
                             int capacity)
{
    __shared__ float xt[P2_PTS][64];
    __shared__ int pts[P2_PTS];
    __shared__ double wbv[4][P2_PTS];
    __shared__ int    wbi[4][P2_PTS];

    int count = *counter;
    if (count > capacity) count = capacity;
    const int tid  = threadIdx.x;
    const int wave = tid >> 6;
    const int lane = tid & 63;

    for (int base = blockIdx.x * P2_PTS; base < count; base += gridDim.x * P2_PTS) {
        int npts = count - base; if (npts > P2_PTS) npts = P2_PTS;
        __syncthreads();                              // prev-iter readers done
        if (tid < P2_PTS) pts[tid] = ulist[base + (tid < npts ? tid : 0)];
        __syncthreads();
        if (tid < P2_PTS * 16) {
            int pt = tid >> 4, q = tid & 15;
            *(float4*)&xt[pt][q * 4] = *(const float4*)(x + (size_t)pts[pt] * DIM + q * 4);
        }
        __syncthreads();

        double bv[P2_PTS]; int bc[P2_PTS];
        #pragma unroll
        for (int pt = 0; pt < P2_PTS; ++pt) { bv[pt] = 1.0e300; bc[pt] = 0; }

        for (int ci = 0; ci < 4; ++ci) {
            const int c = tid + ci * 256;
            const float4* crow = (const float4*)(centers + (size_t)c * DIM);
            double m2 = 0.0;
            double dot[P2_PTS];
            #pragma unroll
            for (int pt = 0; pt < P2_PTS; ++pt) dot[pt] = 0.0;
            for (int kc = 0; kc < 16; ++kc) {
                float4 cv = crow[kc];
                double c0 = cv.x, c1 = cv.y, c2 = cv.z, c3 = cv.w;
                m2 += c0 * c0 + c1 * c1 + c2 * c2 + c3 * c3;
                #pragma unroll
                for (int pt = 0; pt < P2_PTS; ++pt) {
                    float4 xv = *(const float4*)&xt[pt][kc * 4];   // LDS broadcast
                    dot[pt] += c0 * (double)xv.x + c1 * (double)xv.y
                             + c2 * (double)xv.z + c3 * (double)xv.w;
                }
            }
            #pragma unroll
            for (int pt = 0; pt < P2_PTS; ++pt) {
                double s = m2 - 2.0 * dot[pt];
                if (s < bv[pt] || (s == bv[pt] && c < bc[pt])) { bv[pt] = s; bc[pt] = c; }
            }
        }

        // per-wave lexicographic (value, index) reduce, then cross-wave via LDS
        #pragma unroll
        for (int pt = 0; pt < P2_PTS; ++pt) {
            double v = bv[pt]; int i = bc[pt];
            #pragma unroll
            for (int m = 1; m <= 32; m <<= 1) {
                double ov = __shfl_xor(v, m);
                int    oi = __shfl_xor(i, m);
                if (ov < v || (ov == v && oi < i)) { v = ov; i = oi; }
            }
            if (lane == 0) { wbv[wave][pt] = v; wbi[wave][pt] = i; }
        }
        __syncthreads();
        if (tid < npts) {
            double v = wbv[0][tid]; int i = wbi[0][tid];
            #pragma unroll
            for (int w = 1; w < 4; ++w) {
                double ov = wbv[w][tid]; int oi = wbi[w][tid];
                if (ov < v || (ov == v && oi < i)) { v = ov; i = oi; }
            }
            out[pts[tid]] = i;
        }
    }
}

extern "C" void kernel_launch(void* const* d_in, const int* in_sizes, int n_in,
                              void* d_out, int out_size, void* d_ws, size_t ws_size,
                              hipStream_t stream)
{
    const float* x       = (const float*)d_in[0];
    const float* centers = (const float*)d_in[1];
    int* out     = (int*)d_out;
    int* counter = (int*)d_ws;
    int* ulist   = (int*)((char*)d_ws + 64);
    int capacity = (int)((ws_size > 64 ? ws_size - 64 : 0) / sizeof(int));
    if (capacity > N_PTS) capacity = N_PTS;

    hipMemsetAsync(d_ws, 0, 64, stream);
    dim3 g1((N_PTS + 511) / 512);     // 977 blocks x 512 threads
    kmeans_pass1<<<g1, 512, 0, stream>>>(x, centers, out, counter, ulist, capacity);
    kmeans_pass2<<<2048, 256, 0, stream>>>(x, centers, out, counter, ulist, capacity);
}

// Round 3
// 440.524 us; speedup vs baseline: 1.1461x; 1.1461x over previous
//
#include <hip/hip_runtime.h>
#include <hip/hip_bf16.h>

// KMeans predict: ids = argmin_k ||c_k||^2 - 2 x.c_k    (N=500000, D=64, K=1024)
// Pass 1: COMPENSATED fp16 MFMA (hi+lo split of x and c, 3 cross-term MFMAs)
//         -> score noise ~1e-5, margin 1.5e-3 -> ~hundreds of uncertain pts.
//         C-init = -0.5*||c||^2 (fp32). Track best + runner-up per point.
// Pass 2: fp64-exact block-per-point recompute for uncertain points.

#define N_PTS 500000
#define DIM   64
#define K_CENT 1024
#define MARGIN 1.5e-3f   // s~ units; compensated noise bound ~5e-5 -> 30x slack

typedef _Float16 half8 __attribute__((ext_vector_type(8)));
typedef float    floatx4 __attribute__((ext_vector_type(4)));

__device__ __forceinline__ float sel4f(int r, float a, float b, float c, float d) {
    return r == 0 ? a : (r == 1 ? b : (r == 2 ? c : d));
}
__device__ __forceinline__ int sel4i(int r, int a, int b, int c, int d) {
    return r == 0 ? a : (r == 1 ? b : (r == 2 ? c : d));
}

// ---------------------------------------------------------------- pass 1 ----
// 1024 threads = 16 waves; wave handles 32 points (2 M-tiles of 16).
// Centers staged hi+lo fp16 in 8 stages of 128; row stride 144 halves
// (hi at +0, lo at +72) keeps b128 reads at the measured-cheap conflict level.
__launch_bounds__(1024, 4)
__global__ void kmeans_pass1(const float* __restrict__ x,
                             const float* __restrict__ centers,
                             int* __restrict__ out,
                             int* __restrict__ counter,
                             int* __restrict__ ulist,
                             int capacity)
{
    __shared__ __align__(16) _Float16 ldsC[128 * 144];   // 36.9 KB
    __shared__ float negm2[128];

    const int tid  = threadIdx.x;
    const int lane = tid & 63;
    const int wave = tid >> 6;
    const int l15  = lane & 15;
    const int quad = lane >> 4;

    const int baseP = blockIdx.x * 512 + wave * 32;

    // ---- A fragments hi/lo: 2 M-tiles x 2 K-halves. A[m=l15][k=quad*8+j] ----
    half8 ah[2][2], al[2][2];
    #pragma unroll
    for (int mt = 0; mt < 2; ++mt) {
        int p = baseP + mt * 16 + l15;
        if (p > N_PTS - 1) p = N_PTS - 1;            // tail clamp (dup row)
        const float* xr = x + (size_t)p * DIM + quad * 8;
        #pragma unroll
        for (int h = 0; h < 2; ++h) {
            float4 f0 = *(const float4*)(xr + h * 32);
            float4 f1 = *(const float4*)(xr + h * 32 + 4);
            float v[8] = {f0.x, f0.y, f0.z, f0.w, f1.x, f1.y, f1.z, f1.w};
            half8 hi, lo;
            #pragma unroll
            for (int j = 0; j < 8; ++j) {
                _Float16 hj = (_Float16)v[j];
                hi[j] = hj;
                lo[j] = (_Float16)(v[j] - (float)hj);  // exact residual
            }
            ah[mt][h] = hi; al[mt][h] = lo;
        }
    }

    float m1[2][4], m2v[2][4];
    int   ctb[2][4];
    #pragma unroll
    for (int mt = 0; mt < 2; ++mt)
        #pragma unroll
        for (int r = 0; r < 4; ++r) { m1[mt][r] = -1e30f; m2v[mt][r] = -1e30f; ctb[mt][r] = 0; }

    for (int s = 0; s < 8; ++s) {
        __syncthreads();                              // prev-stage readers done
        // ---- stage 128 centers: thread t -> center t>>3, octet t&7 ----
        {
            const int c = tid >> 3, e = tid & 7;
            const float* src = centers + (size_t)(s * 128 + c) * DIM + e * 8;
            float4 f0 = *(const float4*)(src);
            float4 f1 = *(const float4*)(src + 4);
            float v[8] = {f0.x, f0.y, f0.z, f0.w, f1.x, f1.y, f1.z, f1.w};
            float ss = 0.f;
            half8 hi, lo;
            #pragma unroll
            for (int j = 0; j < 8; ++j) {
                ss = fmaf(v[j], v[j], ss);
                _Float16 hj = (_Float16)v[j];
                hi[j] = hj;
                lo[j] = (_Float16)(v[j] - (float)hj);
            }
            *(half8*)&ldsC[c * 144 + e * 8]      = hi;
            *(half8*)&ldsC[c * 144 + 72 + e * 8] = lo;
            ss += __shfl_xor(ss, 1);
            ss += __shfl_xor(ss, 2);
            ss += __shfl_xor(ss, 4);
            if (e == 0) negm2[c] = -0.5f * ss;
        }
        __syncthreads();

        // ---- 8 center-tiles of 16 in this stage ----
        #pragma unroll 2
        for (int ctl = 0; ctl < 8; ++ctl) {
            const float ic = negm2[ctl * 16 + l15];
            const _Float16* bp = &ldsC[(ctl * 16 + l15) * 144 + quad * 8];
            half8 bh0 = *(const half8*)bp;             // hi, k 0..31
            half8 bh1 = *(const half8*)(bp + 32);      // hi, k 32..63
            half8 bl0 = *(const half8*)(bp + 72);      // lo, k 0..31
            half8 bl1 = *(const half8*)(bp + 104);     // lo, k 32..63
            const int ct = s * 8 + ctl;
            #pragma unroll
            for (int mt = 0; mt < 2; ++mt) {
                floatx4 acc = {ic, ic, ic, ic};        // -0.5*||c||^2 (fp32)
                acc = __builtin_amdgcn_mfma_f32_16x16x32_f16(al[mt][0], bh0, acc, 0, 0, 0);
                acc = __builtin_amdgcn_mfma_f32_16x16x32_f16(ah[mt][0], bl0, acc, 0, 0, 0);
                acc = __builtin_amdgcn_mfma_f32_16x16x32_f16(al[mt][1], bh1, acc, 0, 0, 0);
                acc = __builtin_amdgcn_mfma_f32_16x16x32_f16(ah[mt][1], bl1, acc, 0, 0, 0);
                acc = __builtin_amdgcn_mfma_f32_16x16x32_f16(ah[mt][0], bh0, acc, 0, 0, 0);
                acc = __builtin_amdgcn_mfma_f32_16x16x32_f16(ah[mt][1], bh1, acc, 0, 0, 0);
                #pragma unroll
                for (int r = 0; r < 4; ++r) {
                    float sc = acc[r];                 // argmax s~ == argmin score
                    m2v[mt][r] = fmaxf(m2v[mt][r], fminf(sc, m1[mt][r]));
                    bool gt = sc > m1[mt][r];          // strict: first-index ties
                    m1[mt][r] = gt ? sc : m1[mt][r];
                    ctb[mt][r] = gt ? ct : ctb[mt][r];
                }
            }
        }
    }

    // ---- per-point reduce across the 16-lane column group, then write ----
    #pragma unroll
    for (int mt = 0; mt < 2; ++mt) {
        #pragma unroll
        for (int r = 0; r < 4; ++r) {
            float a1 = m1[mt][r], a2 = m2v[mt][r];
            int   id = ctb[mt][r] * 16 + l15;          // full center index
            #pragma unroll
            for (int m = 1; m <= 8; m <<= 1) {
                float o1 = __shfl_xor(a1, m);
                float o2 = __shfl_xor(a2, m);
                int  oid = __shfl_xor(id, m);
                a2 = fmaxf(fmaxf(a2, o2), fminf(a1, o1));
                bool take = (o1 > a1) || (o1 == a1 && oid < id);
                a1 = take ? o1 : a1;
                id = take ? oid : id;
            }
            m1[mt][r] = a1; m2v[mt][r] = a2; ctb[mt][r] = id;
        }
        if (l15 < 4) {                                 // writer lanes: reg = l15
            const int r = l15;
            const int p = baseP + mt * 16 + quad * 4 + r;
            if (p < N_PTS) {
                float a1 = sel4f(r, m1[mt][0], m1[mt][1], m1[mt][2], m1[mt][3]);
                float a2 = sel4f(r, m2v[mt][0], m2v[mt][1], m2v[mt][2], m2v[mt][3]);
                int   id = sel4i(r, ctb[mt][0], ctb[mt][1], ctb[mt][2], ctb[mt][3]);
                out[p] = id;
                if (a1 - a2 < MARGIN) {                // too close -> fp64 recheck
                    int slot = atomicAdd(counter, 1);
                    if (slot < capacity) ulist[slot] = p;
                }
            }
        }
    }
}

// ---------------------------------------------------------------- pass 2 ----
// fp64-exact, one point per block-iteration. x row staged once in LDS
// (broadcast reads); each thread scans 4 centers; lexicographic argmin.
__launch_bounds__(256)
__global__ void kmeans_pass2(const float* __restrict__ x,
                             const float* __restrict__ centers,
                             int* __restrict__ out,
                             const int* __restrict__ counter,
                             const int* __restrict__ ulist,
                             int capacity)
{
    __shared__ float xs[64];
    __shared__ double wv[4];
    __shared__ int    wi[4];

    int count = *counter;
    if (count > capacity) count = capacity;
    const int tid  = threadIdx.x;
    const int lane = tid & 63;
    const int wave = tid >> 6;

    for (int u = blockIdx.x; u < count; u += gridDim.x) {
        __syncthreads();                               // protect xs/wv reuse
        const int p = ulist[u];
        if (tid < 16)
            ((float4*)xs)[tid] = ((const float4*)(x + (size_t)p * DIM))[tid];
        __syncthreads();

        double bv = 1.0e300; int bi = 0;
        #pragma unroll
        for (int j = 0; j < 4; ++j) {
            const int c = tid + j * 256;
            const float4* crow = (const float4*)(centers + (size_t)c * DIM);
            double m2 = 0.0, dot = 0.0;
            #pragma unroll
            for (int kc = 0; kc < 16; ++kc) {
                float4 cv = crow[kc];
                float4 xv = *(const float4*)&xs[kc * 4];   // LDS broadcast
                double c0 = cv.x, c1 = cv.y, c2 = cv.z, c3 = cv.w;
                m2 += c0 * c0 + c1 * c1 + c2 * c2 + c3 * c3;
                dot += c0 * (double)xv.x + c1 * (double)xv.y
                     + c2 * (double)xv.z + c3 * (double)xv.w;
            }
            double s = m2 - 2.0 * dot;
            if (s < bv || (s == bv && c < bi)) { bv = s; bi = c; }
        }
        #pragma unroll
        for (int m = 1; m <= 32; m <<= 1) {
            double ov = __shfl_xor(bv, m);
            int    oi = __shfl_xor(bi, m);
            if (ov < bv || (ov == bv && oi < bi)) { bv = ov; bi = oi; }
        }
        if (lane == 0) { wv[wave] = bv; wi[wave] = bi; }
        __syncthreads();
        if (tid == 0) {
            double v = wv[0]; int i = wi[0];
            #pragma unroll
            for (int w = 1; w < 4; ++w) {
                if (wv[w] < v || (wv[w] == v && wi[w] < i)) { v = wv[w]; i = wi[w]; }
            }
            out[p] = i;
        }
    }
}

extern "C" void kernel_launch(void* const* d_in, const int* in_sizes, int n_in,
                              void* d_out, int out_size, void* d_ws, size_t ws_size,
                              hipStream_t stream)
{
    const float* x       = (const float*)d_in[0];
    const float* centers = (const float*)d_in[1];
    int* out     = (int*)d_out;
    int* counter = (int*)d_ws;
    int* ulist   = (int*)((char*)d_ws + 64);
    int capacity = (int)((ws_size > 64 ? ws_size - 64 : 0) / sizeof(int));
    if (capacity > N_PTS) capacity = N_PTS;

    hipMemsetAsync(d_ws, 0, 64, stream);
    dim3 g1((N_PTS + 511) / 512);     // 977 blocks x 1024 threads, 512 pts each
    kmeans_pass1<<<g1, 1024, 0, stream>>>(x, centers, out, counter, ulist, capacity);
    kmeans_pass2<<<512, 256, 0, stream>>>(x, centers, out, counter, ulist, capacity);
}